// Round 2
// baseline (9654.012 us; speedup 1.0000x reference)
//
#include <hip/hip_runtime.h>
#include <hip/hip_bf16.h>
#include <math.h>

constexpr int T_ = 1 << 18;            // hash table size per level (2^18)
constexpr unsigned TMASK = T_ - 1;
constexpr unsigned PRIME = 2654435761u;

struct NVals { float n[16]; };

__device__ __forceinline__ float leaky_relu(float v) { return v > 0.f ? v : 0.01f * v; }

// One thread per point. Weights in LDS (fp32). Hidden state in registers.
// Output is FLOAT32 (reference returns fp32; round-1 bf16 write was the bug).
__global__ __launch_bounds__(256, 3)
void fused_hashnerf(const float2* __restrict__ X,
                    const float2* __restrict__ table,
                    const float4* __restrict__ W1, const float* __restrict__ b1,
                    const float4* __restrict__ W2, const float* __restrict__ b2,
                    const float4* __restrict__ W3, const float* __restrict__ b3,
                    const float*  __restrict__ W4, const float* __restrict__ b4,
                    float* __restrict__ out,
                    NVals nv)
{
    // W1: (32,64) -> 512 float4 ; W2/W3: (64,64) -> 1024 float4 ; W4: (64,3) padded to float4
    __shared__ float4 sW1[32 * 16];
    __shared__ float4 sW2[64 * 16];
    __shared__ float4 sW3[64 * 16];
    __shared__ float4 sW4[64];
    __shared__ float  sB1[64], sB2[64], sB3[64], sB4[4];

    const int t = threadIdx.x;
    for (int i = t; i < 32 * 16; i += 256) sW1[i] = W1[i];
    for (int i = t; i < 64 * 16; i += 256) sW2[i] = W2[i];
    for (int i = t; i < 64 * 16; i += 256) sW3[i] = W3[i];
    if (t < 64) {
        sB1[t] = b1[t]; sB2[t] = b2[t]; sB3[t] = b3[t];
        sW4[t] = make_float4(W4[t * 3 + 0], W4[t * 3 + 1], W4[t * 3 + 2], 0.f);
    }
    if (t < 3) sB4[t] = b4[t];
    if (t == 3) sB4[3] = 0.f;
    __syncthreads();

    const int i = blockIdx.x * 256 + t;
    const float2 xy = X[i];

    float A[64];
    float B[64];

    // ---- Hash-grid encoding into A[0..31] ----
    // NOTE: reference does x_floor * vertices (multiply, NOT add), so corners are
    // (0,0), (0,yf), (xf,0), (xf,yf). Hash = (x ^ y*PRIME) & (2^18-1), valid in u32
    // (low 18 bits of the int64 product == low 18 bits of the u32 product).
    #pragma unroll
    for (int l = 0; l < 16; ++l) {
        const float n = nv.n[l];
        const float xs = xy.x * n, ys = xy.y * n;
        const float xf = floorf(xs), yf = floorf(ys);
        const float fx = xs - xf, fy = ys - yf;
        const unsigned xi = (unsigned)(int)xf;
        const unsigned yi = (unsigned)(int)yf;
        const unsigned hy = (yi * PRIME) & TMASK;        // corner (0, yf)
        const unsigned hx = xi & TMASK;                  // corner (xf, 0)
        const unsigned h3 = (xi ^ (yi * PRIME)) & TMASK; // corner (xf, yf)

        const float2* tl = table + (size_t)l * T_;
        const float2 v0 = tl[0];
        const float2 v1 = tl[hy];
        const float2 v2 = tl[hx];
        const float2 v3 = tl[h3];

        const float cx = 1.f - fx, cy = 1.f - fy;
        const float w0 = cx * cy, w1 = cx * fy, w2 = fx * cy, w3 = fx * fy;
        A[2 * l + 0] = w0 * v0.x + w1 * v1.x + w2 * v2.x + w3 * v3.x;
        A[2 * l + 1] = w0 * v0.y + w1 * v1.y + w2 * v2.y + w3 * v3.y;
    }

    // ---- Layer 1: B = leaky(b1 + A[0:32] @ W1) ----
    #pragma unroll
    for (int j = 0; j < 64; ++j) B[j] = sB1[j];
    #pragma unroll
    for (int k = 0; k < 32; ++k) {
        const float a = A[k];
        #pragma unroll
        for (int j = 0; j < 16; ++j) {
            const float4 w = sW1[k * 16 + j];
            B[4 * j + 0] += a * w.x; B[4 * j + 1] += a * w.y;
            B[4 * j + 2] += a * w.z; B[4 * j + 3] += a * w.w;
        }
    }
    #pragma unroll
    for (int j = 0; j < 64; ++j) B[j] = leaky_relu(B[j]);

    // ---- Layer 2: A = leaky(b2 + B @ W2) ----
    #pragma unroll
    for (int j = 0; j < 64; ++j) A[j] = sB2[j];
    #pragma unroll
    for (int k = 0; k < 64; ++k) {
        const float a = B[k];
        #pragma unroll
        for (int j = 0; j < 16; ++j) {
            const float4 w = sW2[k * 16 + j];
            A[4 * j + 0] += a * w.x; A[4 * j + 1] += a * w.y;
            A[4 * j + 2] += a * w.z; A[4 * j + 3] += a * w.w;
        }
    }
    #pragma unroll
    for (int j = 0; j < 64; ++j) A[j] = leaky_relu(A[j]);

    // ---- Layer 3: B = leaky(b3 + A @ W3) ----
    #pragma unroll
    for (int j = 0; j < 64; ++j) B[j] = sB3[j];
    #pragma unroll
    for (int k = 0; k < 64; ++k) {
        const float a = A[k];
        #pragma unroll
        for (int j = 0; j < 16; ++j) {
            const float4 w = sW3[k * 16 + j];
            B[4 * j + 0] += a * w.x; B[4 * j + 1] += a * w.y;
            B[4 * j + 2] += a * w.z; B[4 * j + 3] += a * w.w;
        }
    }
    #pragma unroll
    for (int j = 0; j < 64; ++j) B[j] = leaky_relu(B[j]);

    // ---- Layer 4: out = relu(b4 + B @ W4) ----
    float o0 = sB4[0], o1 = sB4[1], o2 = sB4[2];
    #pragma unroll
    for (int k = 0; k < 64; ++k) {
        const float4 w = sW4[k];
        o0 += B[k] * w.x; o1 += B[k] * w.y; o2 += B[k] * w.z;
    }
    out[3 * i + 0] = fmaxf(o0, 0.f);
    out[3 * i + 1] = fmaxf(o1, 0.f);
    out[3 * i + 2] = fmaxf(o2, 0.f);
}

extern "C" void kernel_launch(void* const* d_in, const int* in_sizes, int n_in,
                              void* d_out, int out_size, void* d_ws, size_t ws_size,
                              hipStream_t stream) {
    const float2* X     = (const float2*)d_in[0];
    const float2* table = (const float2*)d_in[1];
    const float4* W1    = (const float4*)d_in[2];
    const float*  b1    = (const float*)d_in[3];
    const float4* W2    = (const float4*)d_in[4];
    const float*  b2    = (const float*)d_in[5];
    const float4* W3    = (const float4*)d_in[6];
    const float*  b3    = (const float*)d_in[7];
    const float*  W4    = (const float*)d_in[8];
    const float*  b4    = (const float*)d_in[9];
    float* out          = (float*)d_out;

    const int npts = in_sizes[0] / 2;  // X is (N,2)

    // Match numpy: b_geo = exp((log(1024)-log(16))/15) in double;
    // N_l = floor(float32(16 * b^l))  (cast to f32 BEFORE floor, as the reference does)
    NVals nv;
    const double bg = exp((log(1024.0) - log(16.0)) / 15.0);
    for (int l = 0; l < 16; ++l)
        nv.n[l] = floorf((float)(16.0 * pow(bg, (double)l)));

    fused_hashnerf<<<npts / 256, 256, 0, stream>>>(X, table, W1, b1, W2, b2, W3, b3,
                                                   W4, b4, out, nv);
}

// Round 3
// 1326.548 us; speedup vs baseline: 7.2775x; 7.2775x over previous
//
#include <hip/hip_runtime.h>
#include <hip/hip_bf16.h>
#include <math.h>

constexpr int T_ = 1 << 18;            // hash table size per level (2^18)
constexpr unsigned TMASK = T_ - 1;
constexpr unsigned PRIME = 2654435761u;

struct NVals { float n[16]; };

__device__ __forceinline__ float leaky_relu(float v) { return v > 0.f ? v : 0.01f * v; }

// One thread per point. Weights in LDS (fp32). Hidden state in registers.
// __launch_bounds__(256,1): round-2's (256,3) capped VGPRs at ~170 -> compiler
// demoted A[]/B[] to scratch -> 31 GB of spill traffic (FETCH==WRITE==15.7GB,
// VALUBusy 1.8%). With min-waves=1 the allocator can take ~200 VGPRs; actual
// occupancy still ~2 waves/EU from real usage.
__global__ __launch_bounds__(256, 1)
void fused_hashnerf(const float2* __restrict__ X,
                    const float2* __restrict__ table,
                    const float4* __restrict__ W1, const float* __restrict__ b1,
                    const float4* __restrict__ W2, const float* __restrict__ b2,
                    const float4* __restrict__ W3, const float* __restrict__ b3,
                    const float*  __restrict__ W4, const float* __restrict__ b4,
                    float* __restrict__ out,
                    NVals nv)
{
    // W1: (32,64) -> 512 float4 ; W2/W3: (64,64) -> 1024 float4 ; W4: (64,3) padded to float4
    __shared__ float4 sW1[32 * 16];
    __shared__ float4 sW2[64 * 16];
    __shared__ float4 sW3[64 * 16];
    __shared__ float4 sW4[64];
    __shared__ float  sB1[64], sB2[64], sB3[64], sB4[4];

    const int t = threadIdx.x;
    for (int i = t; i < 32 * 16; i += 256) sW1[i] = W1[i];
    for (int i = t; i < 64 * 16; i += 256) sW2[i] = W2[i];
    for (int i = t; i < 64 * 16; i += 256) sW3[i] = W3[i];
    if (t < 64) {
        sB1[t] = b1[t]; sB2[t] = b2[t]; sB3[t] = b3[t];
        sW4[t] = make_float4(W4[t * 3 + 0], W4[t * 3 + 1], W4[t * 3 + 2], 0.f);
    }
    if (t < 3) sB4[t] = b4[t];
    if (t == 3) sB4[3] = 0.f;
    __syncthreads();

    const int i = blockIdx.x * 256 + t;
    const float2 xy = X[i];

    float A[64];
    float B[64];

    // ---- Hash-grid encoding into A[0..31] ----
    // Reference does x_floor * vertices (multiply, NOT add): corners are
    // (0,0), (0,yf), (xf,0), (xf,yf). Hash = (x ^ y*PRIME) & (2^18-1), valid in u32.
    #pragma unroll
    for (int l = 0; l < 16; ++l) {
        const float n = nv.n[l];
        const float xs = xy.x * n, ys = xy.y * n;
        const float xf = floorf(xs), yf = floorf(ys);
        const float fx = xs - xf, fy = ys - yf;
        const unsigned xi = (unsigned)(int)xf;
        const unsigned yi = (unsigned)(int)yf;
        const unsigned hy = (yi * PRIME) & TMASK;        // corner (0, yf)
        const unsigned hx = xi & TMASK;                  // corner (xf, 0)
        const unsigned h3 = (xi ^ (yi * PRIME)) & TMASK; // corner (xf, yf)

        const float2* tl = table + (size_t)l * T_;
        const float2 v0 = tl[0];
        const float2 v1 = tl[hy];
        const float2 v2 = tl[hx];
        const float2 v3 = tl[h3];

        const float cx = 1.f - fx, cy = 1.f - fy;
        const float w0 = cx * cy, w1 = cx * fy, w2 = fx * cy, w3 = fx * fy;
        A[2 * l + 0] = w0 * v0.x + w1 * v1.x + w2 * v2.x + w3 * v3.x;
        A[2 * l + 1] = w0 * v0.y + w1 * v1.y + w2 * v2.y + w3 * v3.y;
    }

    // ---- Layer 1: B = leaky(b1 + A[0:32] @ W1) ----
    #pragma unroll
    for (int j = 0; j < 64; ++j) B[j] = sB1[j];
    #pragma unroll
    for (int k = 0; k < 32; ++k) {
        const float a = A[k];
        #pragma unroll
        for (int j = 0; j < 16; ++j) {
            const float4 w = sW1[k * 16 + j];
            B[4 * j + 0] += a * w.x; B[4 * j + 1] += a * w.y;
            B[4 * j + 2] += a * w.z; B[4 * j + 3] += a * w.w;
        }
    }
    #pragma unroll
    for (int j = 0; j < 64; ++j) B[j] = leaky_relu(B[j]);

    // ---- Layer 2: A = leaky(b2 + B @ W2) ----
    #pragma unroll
    for (int j = 0; j < 64; ++j) A[j] = sB2[j];
    #pragma unroll
    for (int k = 0; k < 64; ++k) {
        const float a = B[k];
        #pragma unroll
        for (int j = 0; j < 16; ++j) {
            const float4 w = sW2[k * 16 + j];
            A[4 * j + 0] += a * w.x; A[4 * j + 1] += a * w.y;
            A[4 * j + 2] += a * w.z; A[4 * j + 3] += a * w.w;
        }
    }
    #pragma unroll
    for (int j = 0; j < 64; ++j) A[j] = leaky_relu(A[j]);

    // ---- Layer 3: B = leaky(b3 + A @ W3) ----
    #pragma unroll
    for (int j = 0; j < 64; ++j) B[j] = sB3[j];
    #pragma unroll
    for (int k = 0; k < 64; ++k) {
        const float a = A[k];
        #pragma unroll
        for (int j = 0; j < 16; ++j) {
            const float4 w = sW3[k * 16 + j];
            B[4 * j + 0] += a * w.x; B[4 * j + 1] += a * w.y;
            B[4 * j + 2] += a * w.z; B[4 * j + 3] += a * w.w;
        }
    }
    #pragma unroll
    for (int j = 0; j < 64; ++j) B[j] = leaky_relu(B[j]);

    // ---- Layer 4: out = relu(b4 + B @ W4) ----
    float o0 = sB4[0], o1 = sB4[1], o2 = sB4[2];
    #pragma unroll
    for (int k = 0; k < 64; ++k) {
        const float4 w = sW4[k];
        o0 += B[k] * w.x; o1 += B[k] * w.y; o2 += B[k] * w.z;
    }
    out[3 * i + 0] = fmaxf(o0, 0.f);
    out[3 * i + 1] = fmaxf(o1, 0.f);
    out[3 * i + 2] = fmaxf(o2, 0.f);
}

extern "C" void kernel_launch(void* const* d_in, const int* in_sizes, int n_in,
                              void* d_out, int out_size, void* d_ws, size_t ws_size,
                              hipStream_t stream) {
    const float2* X     = (const float2*)d_in[0];
    const float2* table = (const float2*)d_in[1];
    const float4* W1    = (const float4*)d_in[2];
    const float*  b1    = (const float*)d_in[3];
    const float4* W2    = (const float4*)d_in[4];
    const float*  b2    = (const float*)d_in[5];
    const float4* W3    = (const float4*)d_in[6];
    const float*  b3    = (const float*)d_in[7];
    const float*  W4    = (const float*)d_in[8];
    const float*  b4    = (const float*)d_in[9];
    float* out          = (float*)d_out;

    const int npts = in_sizes[0] / 2;  // X is (N,2)

    // Match numpy: b_geo = exp((log(1024)-log(16))/15) in double;
    // N_l = floor(float32(16 * b^l))  (cast to f32 BEFORE floor, as the reference does)
    NVals nv;
    const double bg = exp((log(1024.0) - log(16.0)) / 15.0);
    for (int l = 0; l < 16; ++l)
        nv.n[l] = floorf((float)(16.0 * pow(bg, (double)l)));

    fused_hashnerf<<<npts / 256, 256, 0, stream>>>(X, table, W1, b1, W2, b2, W3, b3,
                                                   W4, b4, out, nv);
}

// Round 4
// 280.253 us; speedup vs baseline: 34.4475x; 4.7334x over previous
//
#include <hip/hip_runtime.h>
#include <math.h>

typedef _Float16 half8  __attribute__((ext_vector_type(8)));
typedef float    float4v __attribute__((ext_vector_type(4)));

constexpr int T_ = 1 << 18;            // hash table size per level
constexpr unsigned TMASK = T_ - 1;
constexpr unsigned PRIME = 2654435761u;
constexpr int HP = 72;                 // H row pitch in f16 (64 + 8 pad: bank-spread)

// ws layout:
//   [0, 22528)      : 22 W-fragments (f16), frag f: 64 lanes x 8 halfs
//                     frag order: L1 t=0..3 | L2 s0 t0..3, s1 t0..3 | L3 ditto | L4 s0,s1
//   [22528, 23360)  : biases fp32: b1[64] b2[64] b3[64] b4[16] (b4 padded w/ zeros)
//   [23360, 23424)  : N_values fp32 [16]
constexpr int WFRAG_HALFS = 22 * 64 * 8;   // 11264 halfs = 22528 B
constexpr int BIAS_FLOATS = 208;           // 3*64 + 16
constexpr int WS_UINT4    = 23424 / 16;    // 1464

struct NVals { float n[16]; };

// ---------------- prep: swizzle weights into MFMA fragment order ----------------
__global__ void prep_weights(const float* __restrict__ W1, const float* __restrict__ b1,
                             const float* __restrict__ W2, const float* __restrict__ b2,
                             const float* __restrict__ W3, const float* __restrict__ b3,
                             const float* __restrict__ W4, const float* __restrict__ b4,
                             _Float16* __restrict__ wsW, float* __restrict__ wsB, NVals nv)
{
    const int tid = threadIdx.x;
    // A'-fragment (weights-as-A, transposed formulation): lane l holds
    // W[k = 32s + 8*(l>>4) + j][n = 16t + (l&15)], j=0..7 contiguous.
    for (int e = tid; e < WFRAG_HALFS; e += 256) {
        const int frag = e >> 9;         // /512
        const int l    = (e >> 3) & 63;
        const int j    = e & 7;
        const int g = l >> 4, m = l & 15;
        float v;
        if (frag < 4) {                       // L1: W1 (32x64), s=0, t=frag
            v = W1[(8*g + j) * 64 + 16*frag + m];
        } else if (frag < 12) {               // L2: W2 (64x64)
            const int s = (frag - 4) >> 2, t = (frag - 4) & 3;
            v = W2[(32*s + 8*g + j) * 64 + 16*t + m];
        } else if (frag < 20) {               // L3: W3 (64x64)
            const int s = (frag - 12) >> 2, t = (frag - 12) & 3;
            v = W3[(32*s + 8*g + j) * 64 + 16*t + m];
        } else {                              // L4: W4 (64x3), t=0, pad n>=3 with 0
            const int s = frag - 20;
            v = (m < 3) ? W4[(32*s + 8*g + j) * 3 + m] : 0.f;
        }
        wsW[e] = (_Float16)v;
    }
    if (tid < 64) { wsB[tid] = b1[tid]; wsB[64 + tid] = b2[tid]; wsB[128 + tid] = b3[tid]; }
    if (tid >= 64 && tid < 80) { const int r = tid - 64; wsB[192 + r] = (r < 3) ? b4[r] : 0.f; }
    if (tid >= 80 && tid < 96) wsB[BIAS_FLOATS + (tid - 80)] = nv.n[tid - 80];
}

// ---------------- main fused kernel ----------------
// Block = 256 thr = 4 waves. Each wave: 4 tiles of 16 points (64 pts), block = 256 pts.
// Transposed MFMA form: D[n_out][pt] = W^T x H^T ; activations are B-operand
// (B[n=lane&15=point][k=(lane>>4)*8+j]), so the encoder writes fragments directly
// and all H relayout is b64-write / b128-read. Per-wave H buffer -> no __syncthreads
// in the loop (in-order DS pipe + lgkmcnt fences give wave-local RAW ordering).
#define DS_FENCE() __asm__ volatile("s_waitcnt lgkmcnt(0)" ::: "memory")

__global__ __launch_bounds__(256, 2)
void fused_hashnerf_mfma(const float2* __restrict__ X,
                         const float2* __restrict__ table,
                         const uint4* __restrict__ ws,
                         float* __restrict__ out)
{
    __shared__ uint4    sRaw[WS_UINT4];        // W frags (f16) + biases + N_values
    __shared__ _Float16 sH[4][16 * HP];        // per-wave activation buffer

    const int tid = threadIdx.x;
    for (int i = tid; i < WS_UINT4; i += 256) sRaw[i] = ws[i];
    __syncthreads();

    const _Float16* Wl = (const _Float16*)sRaw;
    const float*    Bl = (const float*)(sRaw + (22528 / 16));

    const int wave = tid >> 6, lane = tid & 63;
    const int g = lane >> 4, c = lane & 15;
    _Float16* H = &sH[wave][0];

    // loop-invariant bias fragments: C'[n_out = 16t + 4g + r][pt], init = b[n_out]
    float4v b1f[4], b2f[4], b3f[4], b4f;
    #pragma unroll
    for (int t = 0; t < 4; ++t) {
        b1f[t] = *(const float4v*)(Bl +       16*t + 4*g);
        b2f[t] = *(const float4v*)(Bl +  64 + 16*t + 4*g);
        b3f[t] = *(const float4v*)(Bl + 128 + 16*t + 4*g);
    }
    b4f = *(const float4v*)(Bl + 192 + 4*g);   // zeros for g>0 / n_out>=3
    float nvq[4];
    #pragma unroll
    for (int q = 0; q < 4; ++q) nvq[q] = Bl[BIAS_FLOATS + 4*g + q];

    const int base_pt = blockIdx.x * 256 + wave * 64;

    for (int it = 0; it < 4; ++it) {
        const int p = base_pt + it * 16 + c;
        const float2 xy = X[p];

        // ---- hash-grid encode: lane (g,c) does levels 4g..4g+3 of point c ----
        // == its own B-fragment (k = 8g + 2q + f = 2*level + feature). Reference
        // multiplies floor by vertices: corners (0,0),(0,yf),(xf,0),(xf,yf);
        // hash reduces mod 2^18 -> u32 arithmetic exact.
        half8 feat;
        #pragma unroll
        for (int q = 0; q < 4; ++q) {
            const int lv = 4*g + q;
            const float n = nvq[q];
            const float xs = xy.x * n, ys = xy.y * n;
            const float xf = floorf(xs), yf = floorf(ys);
            const float fx = xs - xf, fy = ys - yf;
            const unsigned xi = (unsigned)(int)xf, yi = (unsigned)(int)yf;
            const unsigned yp = yi * PRIME;
            const float2* tl = table + (size_t)lv * T_;
            const float2 v0 = tl[0];
            const float2 v1 = tl[yp & TMASK];
            const float2 v2 = tl[xi & TMASK];
            const float2 v3 = tl[(xi ^ yp) & TMASK];
            const float cx = 1.f - fx, cy = 1.f - fy;
            const float w0 = cx*cy, w1 = cx*fy, w2 = fx*cy, w3 = fx*fy;
            feat[2*q+0] = (_Float16)(w0*v0.x + w1*v1.x + w2*v2.x + w3*v3.x);
            feat[2*q+1] = (_Float16)(w0*v0.y + w1*v1.y + w2*v2.y + w3*v3.y);
        }

        // ---- L1: acc[t] = W1^T(tile t) x feat + b1 ----
        float4v acc[4];
        #pragma unroll
        for (int t = 0; t < 4; ++t) {
            const half8 wf = *(const half8*)(Wl + (t*64 + lane)*8);
            acc[t] = __builtin_amdgcn_mfma_f32_16x16x32_f16(wf, feat, b1f[t], 0, 0, 0);
        }
        // leaky + f16 + write H[pt c][16t+4g .. +3]  (b64)
        #pragma unroll
        for (int t = 0; t < 4; ++t) {
            union { _Float16 h[4]; float2 f2; } u;
            #pragma unroll
            for (int r = 0; r < 4; ++r) {
                const float v = acc[t][r];
                u.h[r] = (_Float16)(v > 0.f ? v : 0.01f * v);
            }
            *(float2*)(H + c*HP + 16*t + 4*g) = u.f2;
        }
        DS_FENCE();

        // ---- L2 ----
        half8 a0 = *(const half8*)(H + c*HP +      8*g);
        half8 a1 = *(const half8*)(H + c*HP + 32 + 8*g);
        float4v acc2[4];
        #pragma unroll
        for (int t = 0; t < 4; ++t) {
            const half8 w0f = *(const half8*)(Wl + ((4 + t)*64 + lane)*8);
            const half8 w1f = *(const half8*)(Wl + ((8 + t)*64 + lane)*8);
            float4v a = __builtin_amdgcn_mfma_f32_16x16x32_f16(w0f, a0, b2f[t], 0, 0, 0);
            acc2[t]   = __builtin_amdgcn_mfma_f32_16x16x32_f16(w1f, a1, a,      0, 0, 0);
        }
        #pragma unroll
        for (int t = 0; t < 4; ++t) {
            union { _Float16 h[4]; float2 f2; } u;
            #pragma unroll
            for (int r = 0; r < 4; ++r) {
                const float v = acc2[t][r];
                u.h[r] = (_Float16)(v > 0.f ? v : 0.01f * v);
            }
            *(float2*)(H + c*HP + 16*t + 4*g) = u.f2;
        }
        DS_FENCE();

        // ---- L3 ----
        a0 = *(const half8*)(H + c*HP +      8*g);
        a1 = *(const half8*)(H + c*HP + 32 + 8*g);
        float4v acc3[4];
        #pragma unroll
        for (int t = 0; t < 4; ++t) {
            const half8 w0f = *(const half8*)(Wl + ((12 + t)*64 + lane)*8);
            const half8 w1f = *(const half8*)(Wl + ((16 + t)*64 + lane)*8);
            float4v a = __builtin_amdgcn_mfma_f32_16x16x32_f16(w0f, a0, b3f[t], 0, 0, 0);
            acc3[t]   = __builtin_amdgcn_mfma_f32_16x16x32_f16(w1f, a1, a,      0, 0, 0);
        }
        #pragma unroll
        for (int t = 0; t < 4; ++t) {
            union { _Float16 h[4]; float2 f2; } u;
            #pragma unroll
            for (int r = 0; r < 4; ++r) {
                const float v = acc3[t][r];
                u.h[r] = (_Float16)(v > 0.f ? v : 0.01f * v);
            }
            *(float2*)(H + c*HP + 16*t + 4*g) = u.f2;
        }
        DS_FENCE();

        // ---- L4: n_out = 0..2 live in lanes g==0 ----
        a0 = *(const half8*)(H + c*HP +      8*g);
        a1 = *(const half8*)(H + c*HP + 32 + 8*g);
        const half8 w40 = *(const half8*)(Wl + (20*64 + lane)*8);
        const half8 w41 = *(const half8*)(Wl + (21*64 + lane)*8);
        float4v o = __builtin_amdgcn_mfma_f32_16x16x32_f16(w40, a0, b4f, 0, 0, 0);
        o         = __builtin_amdgcn_mfma_f32_16x16x32_f16(w41, a1, o,   0, 0, 0);
        if (g == 0) {
            float* op = out + (size_t)3 * p;
            op[0] = fmaxf(o[0], 0.f);
            op[1] = fmaxf(o[1], 0.f);
            op[2] = fmaxf(o[2], 0.f);
        }
    }
}

extern "C" void kernel_launch(void* const* d_in, const int* in_sizes, int n_in,
                              void* d_out, int out_size, void* d_ws, size_t ws_size,
                              hipStream_t stream) {
    const float2* X     = (const float2*)d_in[0];
    const float2* table = (const float2*)d_in[1];
    const float*  W1    = (const float*)d_in[2];
    const float*  b1    = (const float*)d_in[3];
    const float*  W2    = (const float*)d_in[4];
    const float*  b2    = (const float*)d_in[5];
    const float*  W3    = (const float*)d_in[6];
    const float*  b3    = (const float*)d_in[7];
    const float*  W4    = (const float*)d_in[8];
    const float*  b4    = (const float*)d_in[9];
    float* out          = (float*)d_out;

    const int npts = in_sizes[0] / 2;

    // N_l = floor(float32(16 * b^l)), b computed in double (matches numpy)
    NVals nv;
    const double bg = exp((log(1024.0) - log(16.0)) / 15.0);
    for (int l = 0; l < 16; ++l)
        nv.n[l] = floorf((float)(16.0 * pow(bg, (double)l)));

    _Float16* wsW = (_Float16*)d_ws;
    float*    wsB = (float*)((char*)d_ws + 22528);

    prep_weights<<<1, 256, 0, stream>>>(W1, b1, W2, b2, W3, b3, W4, b4, wsW, wsB, nv);
    fused_hashnerf_mfma<<<npts / 256, 256, 0, stream>>>(X, table, (const uint4*)d_ws, out);
}